// Round 15
// baseline (144.391 us; speedup 1.0000x reference)
//
#include <hip/hip_runtime.h>

#define D 64
#define SCAN_B 256
#define NBUCK 256    // coarse buckets: key >> 9
#define BSH 9
#define BMSK 511     // second-level bins per bucket
#define NCHUNK 256   // edge chunks for count/scatter passes

typedef __attribute__((ext_vector_type(8))) unsigned short ushort8_t;
typedef __attribute__((ext_vector_type(4))) int   i32x4;
typedef __attribute__((ext_vector_type(4))) float f32x4;

__device__ __forceinline__ unsigned short f2bf(float f) {
    unsigned u = __float_as_uint(f);
    unsigned r = (u + 0x7FFFu + ((u >> 16) & 1u)) >> 16;   // RNE
    return (unsigned short)r;
}
__device__ __forceinline__ float uf(unsigned u) { return __uint_as_float(u); }

// ================= Path A: atomic-free two-level counting sort =================

// P1: per (bucket, chunk) counts for dst and src, bucket-major layout.
// 1024 threads, int4 edge reads (epc multiple of 4 -> aligned).
__global__ __launch_bounds__(1024) void p1_count(
        const int* __restrict__ src, const int* __restrict__ dst, int E,
        int epc, int* __restrict__ cnt) {
    __shared__ int cd[NBUCK], cs[NBUCK];
    int c = blockIdx.x;
    int t = threadIdx.x;
    if (t < NBUCK) { cd[t] = 0; cs[t] = 0; }
    __syncthreads();
    int beg = c * epc;
    int end = min(E, beg + epc);
    if (beg < end) {
        int n = end - beg;
        int nq = n >> 2;
        for (int q = t; q < nq; q += 1024) {
            i32x4 s4 = __builtin_nontemporal_load((const i32x4*)(src + beg + q * 4));
            i32x4 d4 = __builtin_nontemporal_load((const i32x4*)(dst + beg + q * 4));
            atomicAdd(&cd[((unsigned)d4[0]) >> BSH], 1);
            atomicAdd(&cd[((unsigned)d4[1]) >> BSH], 1);
            atomicAdd(&cd[((unsigned)d4[2]) >> BSH], 1);
            atomicAdd(&cd[((unsigned)d4[3]) >> BSH], 1);
            atomicAdd(&cs[((unsigned)s4[0]) >> BSH], 1);
            atomicAdd(&cs[((unsigned)s4[1]) >> BSH], 1);
            atomicAdd(&cs[((unsigned)s4[2]) >> BSH], 1);
            atomicAdd(&cs[((unsigned)s4[3]) >> BSH], 1);
        }
        for (int i = beg + nq * 4 + t; i < end; i += 1024) {
            atomicAdd(&cd[((unsigned)dst[i]) >> BSH], 1);
            atomicAdd(&cs[((unsigned)src[i]) >> BSH], 1);
        }
    }
    __syncthreads();
    if (t < NBUCK) {
        cnt[(size_t)t * NCHUNK + c] = cd[t];
        cnt[(size_t)(NBUCK + t) * NCHUNK + c] = cs[t];
    }
}

// scanA: one block per bucket-row (2*NBUCK rows): exclusive scan of NCHUNK counts
// in place; RAW row total -> btot[row].
__global__ void scanA_kernel(int* __restrict__ cnt, int* __restrict__ btot) {
    __shared__ int lds[NCHUNK];
    int g = blockIdx.x;
    int* e = cnt + (size_t)g * NCHUNK;
    int t = threadIdx.x;
    int v = e[t];
    lds[t] = v;
    __syncthreads();
    for (int off = 1; off < NCHUNK; off <<= 1) {
        int add = (t >= off) ? lds[t - off] : 0;
        __syncthreads();
        lds[t] += add;
        __syncthreads();
    }
    int incl = lds[t];
    e[t] = incl - v;                 // exclusive within row
    if (t == NCHUNK - 1) btot[g] = incl;   // raw total (scanned in p2)
}

// P2: scans the 512 raw row totals in LDS (block 0 publishes to btotS), then
// scatters edges into bucket-partitioned arrays via LDS cursors. 1024 threads.
__global__ __launch_bounds__(1024) void p2_scatter(
        const int* __restrict__ src, const int* __restrict__ dst, int E,
        int epc, const int* __restrict__ cnt, const int* __restrict__ btot,
        int* __restrict__ btotS,
        int* __restrict__ packD, unsigned short* __restrict__ srtS) {
    __shared__ int scn[2 * NBUCK];   // 512
    __shared__ int curD[NBUCK], curS[NBUCK];
    int c = blockIdx.x;
    int t = threadIdx.x;
    int raw = 0;
    if (t < 2 * NBUCK) { raw = btot[t]; scn[t] = raw; }
    __syncthreads();
    for (int off = 1; off < 2 * NBUCK; off <<= 1) {
        int v = 0;
        if (t < 2 * NBUCK && t >= off) v = scn[t - off];
        __syncthreads();
        if (t < 2 * NBUCK) scn[t] += v;
        __syncthreads();
    }
    int excl = 0;
    if (t < 2 * NBUCK) excl = scn[t] - raw;
    __syncthreads();
    if (t < 2 * NBUCK) scn[t] = excl;
    __syncthreads();
    if (c == 0 && t < 2 * NBUCK) btotS[t] = excl;
    if (t < NBUCK) {
        curD[t] = scn[t] + cnt[(size_t)t * NCHUNK + c];
        curS[t] = scn[NBUCK + t] + cnt[(size_t)(NBUCK + t) * NCHUNK + c] - E;
    }
    __syncthreads();
    int beg = c * epc;
    int end = min(E, beg + epc);
    for (int i = beg + t; i < end; i += 1024) {
        int d = dst[i], s = src[i];
        int pd = atomicAdd(&curD[((unsigned)d) >> BSH], 1);
        packD[pd] = (s << BSH) | (d & BMSK);
        int ps = atomicAdd(&curS[((unsigned)s) >> BSH], 1);
        srtS[ps] = (unsigned short)(s & BMSK);
    }
}

// P3 merged: blocks [0,NBUCK) place dst CSR (512-bin hist + pair scan);
// blocks [NBUCK,2*NBUCK) compute src norms AND write feat(bf16)=h*norm.
__global__ __launch_bounds__(512) void p3_merged(
        const int* __restrict__ packD, const unsigned short* __restrict__ srtS,
        const int* __restrict__ btot, const float* __restrict__ hp,
        int E, int n_dst, int n_src,
        int* __restrict__ csr, int2* __restrict__ od_arr,
        unsigned short* __restrict__ featb) {
    __shared__ int hist[512];
    __shared__ int scan_s[256];
    __shared__ float nrm[512];
    int blk = blockIdx.x;
    int t = threadIdx.x;
    if (blk < NBUCK) {
        int b = blk;
        int beg = btot[b];
        int end = btot[b + 1];          // btot[NBUCK] == E
        hist[t] = 0;
        __syncthreads();
        for (int i = beg + t; i < end; i += 512)
            atomicAdd(&hist[packD[i] & BMSK], 1);
        __syncthreads();
        int a0 = 0, a1 = 0, p = 0;
        if (t < 256) {
            a0 = hist[2 * t]; a1 = hist[2 * t + 1];
            p = a0 + a1;
            scan_s[t] = p;
        }
        __syncthreads();
        for (int off = 1; off < 256; off <<= 1) {
            int v = 0;
            if (t < 256 && t >= off) v = scan_s[t - off];
            __syncthreads();
            if (t < 256) scan_s[t] += v;
            __syncthreads();
        }
        if (t < 256) {
            int e0 = scan_s[t] - p;
            int dbin0 = b * 512 + 2 * t;
            int dbin1 = dbin0 + 1;
            if (dbin0 < n_dst) od_arr[dbin0] = make_int2(beg + e0, a0);
            if (dbin1 < n_dst) od_arr[dbin1] = make_int2(beg + e0 + a0, a1);
            hist[2 * t] = e0;               // becomes cursor
            hist[2 * t + 1] = e0 + a0;
        }
        __syncthreads();
        for (int i = beg + t; i < end; i += 512) {
            int v = packD[i];
            int pos = beg + atomicAdd(&hist[v & BMSK], 1);
            __builtin_nontemporal_store(v >> BSH, &csr[pos]);
        }
    } else {
        int row = blk;                  // NBUCK..2*NBUCK-1
        int b = blk - NBUCK;
        int beg = btot[row] - E;
        int end = ((row + 1 < 2 * NBUCK) ? btot[row + 1] : 2 * E) - E;
        hist[t] = 0;
        __syncthreads();
        for (int i = beg + t; i < end; i += 512)
            atomicAdd(&hist[srtS[i]], 1);
        __syncthreads();
        {
            int h0 = hist[t]; if (h0 < 1) h0 = 1;
            nrm[t] = 1.0f / (float)h0;
        }
        __syncthreads();
        for (int i = t; i < 512 * 8; i += 512) {
            int r = i >> 3, l8 = i & 7;
            int gsrc = b * 512 + r;
            if (gsrc < n_src) {
                float nm = nrm[r];
                f32x4 v0 = __builtin_nontemporal_load(
                    (const f32x4*)(hp + (size_t)gsrc * 64 + l8 * 8));
                f32x4 v1 = __builtin_nontemporal_load(
                    (const f32x4*)(hp + (size_t)gsrc * 64 + l8 * 8 + 4));
                ushort8_t o;
                o[0] = f2bf(v0[0] * nm); o[1] = f2bf(v0[1] * nm);
                o[2] = f2bf(v0[2] * nm); o[3] = f2bf(v0[3] * nm);
                o[4] = f2bf(v1[0] * nm); o[5] = f2bf(v1[1] * nm);
                o[6] = f2bf(v1[2] * nm); o[7] = f2bf(v1[3] * nm);
                *(ushort8_t*)(featb + (size_t)gsrc * 64 + l8 * 8) = o;
            }
        }
    }
}

#define ACC(v) do { \
    a[0] += uf((v).x << 16); a[1] += uf((v).x & 0xFFFF0000u); \
    a[2] += uf((v).y << 16); a[3] += uf((v).y & 0xFFFF0000u); \
    a[4] += uf((v).z << 16); a[5] += uf((v).z & 0xFFFF0000u); \
    a[6] += uf((v).w << 16); a[7] += uf((v).w & 0xFFFF0000u); } while (0)

// gather: TWO rows per wave (32 lanes/row); 4 edge-groups x 8 lanes x 16B,
// unroll 4 -> 16 edges in flight per row (32 per wave). NT stores for out.
__global__ void gather_feat(const unsigned short* __restrict__ featb,
                            const int* __restrict__ csr,
                            const int2* __restrict__ od_arr,
                            float* __restrict__ outp, int n_dst) {
    int gid = blockIdx.x * blockDim.x + threadIdx.x;
    int row = gid >> 5;
    if (row >= n_dst) return;
    int lane = threadIdx.x & 31;
    int g = lane >> 3;       // edge group 0..3
    int l8 = lane & 7;       // 16B slot within 128B row
    int2 od = od_arr[row];
    int beg = od.x, dg = od.y;
    int end = beg + dg;
    float a[8] = {0.f, 0.f, 0.f, 0.f, 0.f, 0.f, 0.f, 0.f};
    int k = beg + g;
    for (; k + 12 < end; k += 16) {
        int s0 = __builtin_nontemporal_load(&csr[k]);
        int s1 = __builtin_nontemporal_load(&csr[k + 4]);
        int s2 = __builtin_nontemporal_load(&csr[k + 8]);
        int s3 = __builtin_nontemporal_load(&csr[k + 12]);
        uint4 v0 = *(const uint4*)(featb + (size_t)s0 * 64 + l8 * 8);
        uint4 v1 = *(const uint4*)(featb + (size_t)s1 * 64 + l8 * 8);
        uint4 v2 = *(const uint4*)(featb + (size_t)s2 * 64 + l8 * 8);
        uint4 v3 = *(const uint4*)(featb + (size_t)s3 * 64 + l8 * 8);
        ACC(v0); ACC(v1); ACC(v2); ACC(v3);
    }
    for (; k < end; k += 4) {
        int s0 = __builtin_nontemporal_load(&csr[k]);
        uint4 v0 = *(const uint4*)(featb + (size_t)s0 * 64 + l8 * 8);
        ACC(v0);
    }
    // reduce across the 4 groups (lane bits 3,4) — stays within 32-lane half
    #pragma unroll
    for (int j = 0; j < 8; ++j) a[j] += __shfl_xor(a[j], 8);
    #pragma unroll
    for (int j = 0; j < 8; ++j) a[j] += __shfl_xor(a[j], 16);
    if (g == 0) {
        float nd = 1.0f / (float)(dg < 1 ? 1 : dg);
        f32x4 r0, r1;
        r0[0] = a[0] * nd; r0[1] = a[1] * nd; r0[2] = a[2] * nd; r0[3] = a[3] * nd;
        r1[0] = a[4] * nd; r1[1] = a[5] * nd; r1[2] = a[6] * nd; r1[3] = a[7] * nd;
        __builtin_nontemporal_store(r0, (f32x4*)(outp + (size_t)row * 64 + l8 * 8));
        __builtin_nontemporal_store(r1, (f32x4*)(outp + (size_t)row * 64 + l8 * 8 + 4));
    }
}

// ====================== legacy kernels (paths B/C) ======================
__global__ void scan1_kernel(const int* __restrict__ deg, int n,
                             int* __restrict__ out, int* __restrict__ bsums) {
    __shared__ int tmp[SCAN_B];
    int t = blockIdx.x * SCAN_B + threadIdx.x;
    int v = (t < n) ? deg[t] : 0;
    tmp[threadIdx.x] = v;
    __syncthreads();
    for (int off = 1; off < SCAN_B; off <<= 1) {
        int add = (threadIdx.x >= off) ? tmp[threadIdx.x - off] : 0;
        __syncthreads();
        tmp[threadIdx.x] += add;
        __syncthreads();
    }
    if (t < n) out[t] = tmp[threadIdx.x] - v;
    if (threadIdx.x == SCAN_B - 1) bsums[blockIdx.x] = tmp[threadIdx.x];
}

__global__ void scan2_kernel(int* __restrict__ bsums, int nb) {
    __shared__ int tmp[1024];
    __shared__ int carry_s;
    if (threadIdx.x == 0) carry_s = 0;
    __syncthreads();
    for (int base = 0; base < nb; base += 1024) {
        int i = base + threadIdx.x;
        int v = (i < nb) ? bsums[i] : 0;
        tmp[threadIdx.x] = v;
        __syncthreads();
        for (int off = 1; off < 1024; off <<= 1) {
            int add = (threadIdx.x >= off) ? tmp[threadIdx.x - off] : 0;
            __syncthreads();
            tmp[threadIdx.x] += add;
            __syncthreads();
        }
        int incl = tmp[threadIdx.x];
        int carry = carry_s;
        if (i < nb) bsums[i] = incl - v + carry;
        __syncthreads();
        if (threadIdx.x == 0) carry_s = carry + tmp[1023];
        __syncthreads();
    }
}

__global__ void scan3_kernel(int* __restrict__ out, const int* __restrict__ bsums, int n) {
    int t = blockIdx.x * SCAN_B + threadIdx.x;
    if (t < n) out[t] += bsums[blockIdx.x];
}

__global__ void gather_kernel(const float4* __restrict__ h4, const int* __restrict__ csr_src,
                              const int* __restrict__ offset, const int* __restrict__ deg_dst,
                              const float* __restrict__ norm_src,
                              float4* __restrict__ out4, int n_dst) {
    int gid = blockIdx.x * blockDim.x + threadIdx.x;
    int row = gid >> 6;
    if (row >= n_dst) return;
    int lane = threadIdx.x & 63;
    int g = lane >> 4;
    int l16 = lane & 15;
    int beg = offset[row];
    int deg = deg_dst[row];
    int end = beg + deg;
    float ax = 0.f, ay = 0.f, az = 0.f, aw = 0.f;
    for (int k = beg + g; k < end; k += 4) {
        int s = csr_src[k];
        float ns = norm_src[s];
        float4 v = h4[s * 16 + l16];
        ax = fmaf(v.x, ns, ax);
        ay = fmaf(v.y, ns, ay);
        az = fmaf(v.z, ns, az);
        aw = fmaf(v.w, ns, aw);
    }
    ax += __shfl_xor(ax, 16); ay += __shfl_xor(ay, 16);
    az += __shfl_xor(az, 16); aw += __shfl_xor(aw, 16);
    ax += __shfl_xor(ax, 32); ay += __shfl_xor(ay, 32);
    az += __shfl_xor(az, 32); aw += __shfl_xor(aw, 32);
    if (g == 0) {
        int dg = deg < 1 ? 1 : deg;
        float nd = 1.0f / (float)dg;
        float4 r;
        r.x = ax * nd; r.y = ay * nd; r.z = az * nd; r.w = aw * nd;
        out4[row * 16 + l16] = r;
    }
}

__global__ void degree_kernel(const int* __restrict__ src, const int* __restrict__ dst,
                              int E, int* __restrict__ deg_src, int* __restrict__ deg_dst) {
    int t = blockIdx.x * blockDim.x + threadIdx.x;
    int base = t * 4;
    if (base + 3 < E) {
        int4 s = *(const int4*)(src + base);
        int4 d = *(const int4*)(dst + base);
        atomicAdd(&deg_src[s.x], 1); atomicAdd(&deg_src[s.y], 1);
        atomicAdd(&deg_src[s.z], 1); atomicAdd(&deg_src[s.w], 1);
        atomicAdd(&deg_dst[d.x], 1); atomicAdd(&deg_dst[d.y], 1);
        atomicAdd(&deg_dst[d.z], 1); atomicAdd(&deg_dst[d.w], 1);
    } else {
        for (int i = base; i < E; ++i) {
            atomicAdd(&deg_src[src[i]], 1);
            atomicAdd(&deg_dst[dst[i]], 1);
        }
    }
}

__global__ void norm_src_kernel(const int* __restrict__ deg_src, int n_src,
                                float* __restrict__ norm_src) {
    int t = blockIdx.x * blockDim.x + threadIdx.x;
    if (t < n_src) {
        int s = deg_src[t]; if (s < 1) s = 1;
        norm_src[t] = 1.0f / (float)s;
    }
}

__global__ void fill_kernel(const int* __restrict__ src, const int* __restrict__ dst, int E,
                            const int* __restrict__ offset, int* __restrict__ cursor,
                            int* __restrict__ csr_src) {
    int t = blockIdx.x * blockDim.x + threadIdx.x;
    int base = t * 4;
    if (base + 3 < E) {
        int4 s = *(const int4*)(src + base);
        int4 d = *(const int4*)(dst + base);
        int p;
        p = offset[d.x] + atomicAdd(&cursor[d.x], 1); csr_src[p] = s.x;
        p = offset[d.y] + atomicAdd(&cursor[d.y], 1); csr_src[p] = s.y;
        p = offset[d.z] + atomicAdd(&cursor[d.z], 1); csr_src[p] = s.z;
        p = offset[d.w] + atomicAdd(&cursor[d.w], 1); csr_src[p] = s.w;
    } else {
        for (int i = base; i < E; ++i) {
            int d = dst[i];
            int p = offset[d] + atomicAdd(&cursor[d], 1);
            csr_src[p] = src[i];
        }
    }
}

__global__ void scatter_kernel(const float* __restrict__ h,
                               const int* __restrict__ src, const int* __restrict__ dst,
                               const float* __restrict__ norm_src,
                               float* __restrict__ out, int E) {
    long long t = (long long)blockIdx.x * blockDim.x + threadIdx.x;
    int e = (int)(t >> 6);
    if (e >= E) return;
    int j = (int)(t & 63);
    int s = src[e];
    float v = h[s * D + j] * norm_src[s];
    unsafeAtomicAdd(&out[dst[e] * D + j], v);
}

__global__ void scale_kernel(float* __restrict__ out, const int* __restrict__ deg_dst, int n) {
    int t = blockIdx.x * blockDim.x + threadIdx.x;
    if (t < n) {
        int dg = deg_dst[t >> 6]; if (dg < 1) dg = 1;
        out[t] *= 1.0f / (float)dg;
    }
}

static inline size_t align16(size_t x) { return (x + 15) & ~(size_t)15; }

extern "C" void kernel_launch(void* const* d_in, const int* in_sizes, int n_in,
                              void* d_out, int out_size, void* d_ws, size_t ws_size,
                              hipStream_t stream) {
    const float* h   = (const float*)d_in[0];
    const int*   src = (const int*)d_in[1];
    const int*   dst = (const int*)d_in[2];
    float* out = (float*)d_out;

    const int E     = in_sizes[1];
    const int n_src = in_sizes[0] / D;
    const int n_dst = out_size / D;
    const int n_cnt = 2 * NBUCK * NCHUNK;            // 131072
    int epc = (E + NCHUNK - 1) / NCHUNK;
    epc = (epc + 3) & ~3;                            // 16B-aligned chunk bases

    // ---- Path A: radix-256/512 sort + bf16-feat precompute + 2-row gather ----
    char* w = (char*)d_ws;
    size_t off = 0;
    size_t o_cnt   = off; off = align16(off + (size_t)n_cnt * 4);
    size_t o_btot  = off; off = align16(off + (size_t)(2 * NBUCK) * 4);
    size_t o_btotS = off; off = align16(off + (size_t)(2 * NBUCK) * 4);
    size_t o_packD = off; off = align16(off + (size_t)E * 4);
    size_t o_csr   = off; off = align16(off + (size_t)E * 4);
    size_t o_od    = off; off = align16(off + (size_t)n_dst * 8);
    size_t o_feat  = off; off = align16(off + (size_t)n_src * 64 * 2);
    size_t o_srtS  = off; off = align16(off + (size_t)E * 2);
    size_t needA = off;

    if (ws_size >= needA && n_src <= NBUCK * 512 && n_dst <= NBUCK * 512) {
        int* cnt    = (int*)(w + o_cnt);
        int* btot   = (int*)(w + o_btot);
        int* btotS  = (int*)(w + o_btotS);
        int* packD  = (int*)(w + o_packD);
        int* csr    = (int*)(w + o_csr);
        int2* od    = (int2*)(w + o_od);
        unsigned short* featb = (unsigned short*)(w + o_feat);
        unsigned short* srtS  = (unsigned short*)(w + o_srtS);

        p1_count<<<NCHUNK, 1024, 0, stream>>>(src, dst, E, epc, cnt);
        scanA_kernel<<<2 * NBUCK, NCHUNK, 0, stream>>>(cnt, btot);
        p2_scatter<<<NCHUNK, 1024, 0, stream>>>(src, dst, E, epc, cnt, btot, btotS,
                                                packD, srtS);
        p3_merged<<<2 * NBUCK, 512, 0, stream>>>(packD, srtS, btotS, h,
                                                 E, n_dst, n_src, csr, od, featb);
        long long gthreads = (long long)n_dst * 32;
        gather_feat<<<(int)((gthreads + 255) / 256), 256, 0, stream>>>(
            featb, csr, od, out, n_dst);
        return;
    }

    // ---- Path B: CSR via device atomics ----
    const int nbB = (n_dst + SCAN_B - 1) / SCAN_B;
    const int nbB_pad = ((nbB + 1023) / 1024) * 1024;
    const int eb4 = (E + 4 * 256 - 1) / (4 * 256);
    const int nblk = ((n_src > n_dst ? n_src : n_dst) + 255) / 256;
    size_t needB = ((size_t)n_src * 2 + (size_t)n_dst * 3 + nbB_pad) * 4 + (size_t)E * 4;

    if (ws_size >= needB) {
        int* deg_src = (int*)d_ws;
        int* deg_dst = deg_src + n_src;
        int* cursor  = deg_dst + n_dst;
        int* offset  = cursor + n_dst;
        int* bsums   = offset + n_dst;
        float* norm_src = (float*)(bsums + nbB_pad);
        int* csr_src = (int*)(norm_src + n_src);

        (void)hipMemsetAsync(d_ws, 0, sizeof(int) * (size_t)(n_src + 2 * (size_t)n_dst), stream);
        degree_kernel<<<eb4, 256, 0, stream>>>(src, dst, E, deg_src, deg_dst);
        norm_src_kernel<<<nblk, 256, 0, stream>>>(deg_src, n_src, norm_src);
        scan1_kernel<<<nbB, SCAN_B, 0, stream>>>(deg_dst, n_dst, offset, bsums);
        scan2_kernel<<<1, 1024, 0, stream>>>(bsums, nbB);
        scan3_kernel<<<nbB, SCAN_B, 0, stream>>>(offset, bsums, n_dst);
        fill_kernel<<<eb4, 256, 0, stream>>>(src, dst, E, offset, cursor, csr_src);
        long long gthreads = (long long)n_dst * D;
        gather_kernel<<<(int)((gthreads + 255) / 256), 256, 0, stream>>>(
            (const float4*)h, csr_src, offset, deg_dst, norm_src, (float4*)out, n_dst);
        return;
    }

    // ---- Path C: minimal atomic scatter ----
    {
        int* deg_src = (int*)d_ws;
        int* deg_dst = deg_src + n_src;
        float* norm_src = (float*)(deg_dst + n_dst);
        (void)hipMemsetAsync(d_ws, 0, sizeof(int) * (size_t)(n_src + n_dst), stream);
        (void)hipMemsetAsync(d_out, 0, sizeof(float) * (size_t)out_size, stream);
        degree_kernel<<<eb4, 256, 0, stream>>>(src, dst, E, deg_src, deg_dst);
        norm_src_kernel<<<nblk, 256, 0, stream>>>(deg_src, n_src, norm_src);
        long long total = (long long)E * D;
        scatter_kernel<<<(int)((total + 255) / 256), 256, 0, stream>>>(h, src, dst, norm_src, out, E);
        scale_kernel<<<(out_size + 255) / 256, 256, 0, stream>>>(out, deg_dst, out_size);
    }
}

// Round 16
// 105.524 us; speedup vs baseline: 1.3683x; 1.3683x over previous
//
#include <hip/hip_runtime.h>

#define D 64
#define SCAN_B 256
#define NBUCK 256    // coarse buckets: key >> 9
#define BSH 9
#define BMSK 511     // second-level bins per bucket
#define NCHUNK 256   // edge chunks for count/scatter passes

typedef __attribute__((ext_vector_type(8))) unsigned short ushort8_t;
typedef __attribute__((ext_vector_type(4))) int   i32x4;
typedef __attribute__((ext_vector_type(4))) float f32x4;

__device__ __forceinline__ unsigned short f2bf(float f) {
    unsigned u = __float_as_uint(f);
    unsigned r = (u + 0x7FFFu + ((u >> 16) & 1u)) >> 16;   // RNE
    return (unsigned short)r;
}
__device__ __forceinline__ float uf(unsigned u) { return __uint_as_float(u); }

// ================= Path A: atomic-free two-level counting sort =================

// P1: per (bucket, chunk) counts for dst and src, bucket-major layout.
// 1024 threads, int4 edge reads (epc multiple of 4 -> aligned).
__global__ __launch_bounds__(1024) void p1_count(
        const int* __restrict__ src, const int* __restrict__ dst, int E,
        int epc, int* __restrict__ cnt) {
    __shared__ int cd[NBUCK], cs[NBUCK];
    int c = blockIdx.x;
    int t = threadIdx.x;
    if (t < NBUCK) { cd[t] = 0; cs[t] = 0; }
    __syncthreads();
    int beg = c * epc;
    int end = min(E, beg + epc);
    if (beg < end) {
        int n = end - beg;
        int nq = n >> 2;
        for (int q = t; q < nq; q += 1024) {
            i32x4 s4 = __builtin_nontemporal_load((const i32x4*)(src + beg + q * 4));
            i32x4 d4 = __builtin_nontemporal_load((const i32x4*)(dst + beg + q * 4));
            atomicAdd(&cd[((unsigned)d4[0]) >> BSH], 1);
            atomicAdd(&cd[((unsigned)d4[1]) >> BSH], 1);
            atomicAdd(&cd[((unsigned)d4[2]) >> BSH], 1);
            atomicAdd(&cd[((unsigned)d4[3]) >> BSH], 1);
            atomicAdd(&cs[((unsigned)s4[0]) >> BSH], 1);
            atomicAdd(&cs[((unsigned)s4[1]) >> BSH], 1);
            atomicAdd(&cs[((unsigned)s4[2]) >> BSH], 1);
            atomicAdd(&cs[((unsigned)s4[3]) >> BSH], 1);
        }
        for (int i = beg + nq * 4 + t; i < end; i += 1024) {
            atomicAdd(&cd[((unsigned)dst[i]) >> BSH], 1);
            atomicAdd(&cs[((unsigned)src[i]) >> BSH], 1);
        }
    }
    __syncthreads();
    if (t < NBUCK) {
        cnt[(size_t)t * NCHUNK + c] = cd[t];
        cnt[(size_t)(NBUCK + t) * NCHUNK + c] = cs[t];
    }
}

// scanA: one block per bucket-row (2*NBUCK rows): exclusive scan of NCHUNK counts
// in place; RAW row total -> btot[row].
__global__ void scanA_kernel(int* __restrict__ cnt, int* __restrict__ btot) {
    __shared__ int lds[NCHUNK];
    int g = blockIdx.x;
    int* e = cnt + (size_t)g * NCHUNK;
    int t = threadIdx.x;
    int v = e[t];
    lds[t] = v;
    __syncthreads();
    for (int off = 1; off < NCHUNK; off <<= 1) {
        int add = (t >= off) ? lds[t - off] : 0;
        __syncthreads();
        lds[t] += add;
        __syncthreads();
    }
    int incl = lds[t];
    e[t] = incl - v;                 // exclusive within row
    if (t == NCHUNK - 1) btot[g] = incl;   // raw total (scanned in p2)
}

// P2: scans the 512 raw row totals in LDS (block 0 publishes to btotS), then
// scatters edges into bucket-partitioned arrays via LDS cursors. 1024 threads.
__global__ __launch_bounds__(1024) void p2_scatter(
        const int* __restrict__ src, const int* __restrict__ dst, int E,
        int epc, const int* __restrict__ cnt, const int* __restrict__ btot,
        int* __restrict__ btotS,
        int* __restrict__ packD, unsigned short* __restrict__ srtS) {
    __shared__ int scn[2 * NBUCK];   // 512
    __shared__ int curD[NBUCK], curS[NBUCK];
    int c = blockIdx.x;
    int t = threadIdx.x;
    int raw = 0;
    if (t < 2 * NBUCK) { raw = btot[t]; scn[t] = raw; }
    __syncthreads();
    for (int off = 1; off < 2 * NBUCK; off <<= 1) {
        int v = 0;
        if (t < 2 * NBUCK && t >= off) v = scn[t - off];
        __syncthreads();
        if (t < 2 * NBUCK) scn[t] += v;
        __syncthreads();
    }
    int excl = 0;
    if (t < 2 * NBUCK) excl = scn[t] - raw;
    __syncthreads();
    if (t < 2 * NBUCK) scn[t] = excl;
    __syncthreads();
    if (c == 0 && t < 2 * NBUCK) btotS[t] = excl;
    if (t < NBUCK) {
        curD[t] = scn[t] + cnt[(size_t)t * NCHUNK + c];
        curS[t] = scn[NBUCK + t] + cnt[(size_t)(NBUCK + t) * NCHUNK + c] - E;
    }
    __syncthreads();
    int beg = c * epc;
    int end = min(E, beg + epc);
    for (int i = beg + t; i < end; i += 1024) {
        int d = dst[i], s = src[i];
        int pd = atomicAdd(&curD[((unsigned)d) >> BSH], 1);
        packD[pd] = (s << BSH) | (d & BMSK);
        int ps = atomicAdd(&curS[((unsigned)s) >> BSH], 1);
        srtS[ps] = (unsigned short)(s & BMSK);
    }
}

// P3 merged: blocks [0,NBUCK) place dst CSR (512-bin hist + pair scan);
// blocks [NBUCK,2*NBUCK) compute src norms AND write feat(bf16)=h*norm.
__global__ __launch_bounds__(512) void p3_merged(
        const int* __restrict__ packD, const unsigned short* __restrict__ srtS,
        const int* __restrict__ btot, const float* __restrict__ hp,
        int E, int n_dst, int n_src,
        int* __restrict__ csr, int2* __restrict__ od_arr,
        unsigned short* __restrict__ featb) {
    __shared__ int hist[512];
    __shared__ int scan_s[256];
    __shared__ float nrm[512];
    int blk = blockIdx.x;
    int t = threadIdx.x;
    if (blk < NBUCK) {
        int b = blk;
        int beg = btot[b];
        int end = btot[b + 1];          // btot[NBUCK] == E
        hist[t] = 0;
        __syncthreads();
        for (int i = beg + t; i < end; i += 512)
            atomicAdd(&hist[packD[i] & BMSK], 1);
        __syncthreads();
        int a0 = 0, a1 = 0, p = 0;
        if (t < 256) {
            a0 = hist[2 * t]; a1 = hist[2 * t + 1];
            p = a0 + a1;
            scan_s[t] = p;
        }
        __syncthreads();
        for (int off = 1; off < 256; off <<= 1) {
            int v = 0;
            if (t < 256 && t >= off) v = scan_s[t - off];
            __syncthreads();
            if (t < 256) scan_s[t] += v;
            __syncthreads();
        }
        if (t < 256) {
            int e0 = scan_s[t] - p;
            int dbin0 = b * 512 + 2 * t;
            int dbin1 = dbin0 + 1;
            if (dbin0 < n_dst) od_arr[dbin0] = make_int2(beg + e0, a0);
            if (dbin1 < n_dst) od_arr[dbin1] = make_int2(beg + e0 + a0, a1);
            hist[2 * t] = e0;               // becomes cursor
            hist[2 * t + 1] = e0 + a0;
        }
        __syncthreads();
        for (int i = beg + t; i < end; i += 512) {
            int v = packD[i];
            int pos = beg + atomicAdd(&hist[v & BMSK], 1);
            csr[pos] = v >> BSH;            // regular store: L2 coalesces
        }
    } else {
        int row = blk;                  // NBUCK..2*NBUCK-1
        int b = blk - NBUCK;
        int beg = btot[row] - E;
        int end = ((row + 1 < 2 * NBUCK) ? btot[row + 1] : 2 * E) - E;
        hist[t] = 0;
        __syncthreads();
        for (int i = beg + t; i < end; i += 512)
            atomicAdd(&hist[srtS[i]], 1);
        __syncthreads();
        {
            int h0 = hist[t]; if (h0 < 1) h0 = 1;
            nrm[t] = 1.0f / (float)h0;
        }
        __syncthreads();
        for (int i = t; i < 512 * 8; i += 512) {
            int r = i >> 3, l8 = i & 7;
            int gsrc = b * 512 + r;
            if (gsrc < n_src) {
                float nm = nrm[r];
                f32x4 v0 = __builtin_nontemporal_load(
                    (const f32x4*)(hp + (size_t)gsrc * 64 + l8 * 8));
                f32x4 v1 = __builtin_nontemporal_load(
                    (const f32x4*)(hp + (size_t)gsrc * 64 + l8 * 8 + 4));
                ushort8_t o;
                o[0] = f2bf(v0[0] * nm); o[1] = f2bf(v0[1] * nm);
                o[2] = f2bf(v0[2] * nm); o[3] = f2bf(v0[3] * nm);
                o[4] = f2bf(v1[0] * nm); o[5] = f2bf(v1[1] * nm);
                o[6] = f2bf(v1[2] * nm); o[7] = f2bf(v1[3] * nm);
                *(ushort8_t*)(featb + (size_t)gsrc * 64 + l8 * 8) = o;
            }
        }
    }
}

#define ACC(v) do { \
    a[0] += uf((v).x << 16); a[1] += uf((v).x & 0xFFFF0000u); \
    a[2] += uf((v).y << 16); a[3] += uf((v).y & 0xFFFF0000u); \
    a[4] += uf((v).z << 16); a[5] += uf((v).z & 0xFFFF0000u); \
    a[6] += uf((v).w << 16); a[7] += uf((v).w & 0xFFFF0000u); } while (0)

// gather: TWO rows per wave (32 lanes/row); 4 edge-groups x 8 lanes x 16B,
// unroll 4 -> 16 edges in flight per row (32 per wave). NT stores for out.
__global__ void gather_feat(const unsigned short* __restrict__ featb,
                            const int* __restrict__ csr,
                            const int2* __restrict__ od_arr,
                            float* __restrict__ outp, int n_dst) {
    int gid = blockIdx.x * blockDim.x + threadIdx.x;
    int row = gid >> 5;
    if (row >= n_dst) return;
    int lane = threadIdx.x & 31;
    int g = lane >> 3;       // edge group 0..3
    int l8 = lane & 7;       // 16B slot within 128B row
    int2 od = od_arr[row];
    int beg = od.x, dg = od.y;
    int end = beg + dg;
    float a[8] = {0.f, 0.f, 0.f, 0.f, 0.f, 0.f, 0.f, 0.f};
    int k = beg + g;
    for (; k + 12 < end; k += 16) {
        int s0 = __builtin_nontemporal_load(&csr[k]);
        int s1 = __builtin_nontemporal_load(&csr[k + 4]);
        int s2 = __builtin_nontemporal_load(&csr[k + 8]);
        int s3 = __builtin_nontemporal_load(&csr[k + 12]);
        uint4 v0 = *(const uint4*)(featb + (size_t)s0 * 64 + l8 * 8);
        uint4 v1 = *(const uint4*)(featb + (size_t)s1 * 64 + l8 * 8);
        uint4 v2 = *(const uint4*)(featb + (size_t)s2 * 64 + l8 * 8);
        uint4 v3 = *(const uint4*)(featb + (size_t)s3 * 64 + l8 * 8);
        ACC(v0); ACC(v1); ACC(v2); ACC(v3);
    }
    for (; k < end; k += 4) {
        int s0 = __builtin_nontemporal_load(&csr[k]);
        uint4 v0 = *(const uint4*)(featb + (size_t)s0 * 64 + l8 * 8);
        ACC(v0);
    }
    // reduce across the 4 groups (lane bits 3,4) — stays within 32-lane half
    #pragma unroll
    for (int j = 0; j < 8; ++j) a[j] += __shfl_xor(a[j], 8);
    #pragma unroll
    for (int j = 0; j < 8; ++j) a[j] += __shfl_xor(a[j], 16);
    if (g == 0) {
        float nd = 1.0f / (float)(dg < 1 ? 1 : dg);
        f32x4 r0, r1;
        r0[0] = a[0] * nd; r0[1] = a[1] * nd; r0[2] = a[2] * nd; r0[3] = a[3] * nd;
        r1[0] = a[4] * nd; r1[1] = a[5] * nd; r1[2] = a[6] * nd; r1[3] = a[7] * nd;
        __builtin_nontemporal_store(r0, (f32x4*)(outp + (size_t)row * 64 + l8 * 8));
        __builtin_nontemporal_store(r1, (f32x4*)(outp + (size_t)row * 64 + l8 * 8 + 4));
    }
}

// ====================== legacy kernels (paths B/C) ======================
__global__ void scan1_kernel(const int* __restrict__ deg, int n,
                             int* __restrict__ out, int* __restrict__ bsums) {
    __shared__ int tmp[SCAN_B];
    int t = blockIdx.x * SCAN_B + threadIdx.x;
    int v = (t < n) ? deg[t] : 0;
    tmp[threadIdx.x] = v;
    __syncthreads();
    for (int off = 1; off < SCAN_B; off <<= 1) {
        int add = (threadIdx.x >= off) ? tmp[threadIdx.x - off] : 0;
        __syncthreads();
        tmp[threadIdx.x] += add;
        __syncthreads();
    }
    if (t < n) out[t] = tmp[threadIdx.x] - v;
    if (threadIdx.x == SCAN_B - 1) bsums[blockIdx.x] = tmp[threadIdx.x];
}

__global__ void scan2_kernel(int* __restrict__ bsums, int nb) {
    __shared__ int tmp[1024];
    __shared__ int carry_s;
    if (threadIdx.x == 0) carry_s = 0;
    __syncthreads();
    for (int base = 0; base < nb; base += 1024) {
        int i = base + threadIdx.x;
        int v = (i < nb) ? bsums[i] : 0;
        tmp[threadIdx.x] = v;
        __syncthreads();
        for (int off = 1; off < 1024; off <<= 1) {
            int add = (threadIdx.x >= off) ? tmp[threadIdx.x - off] : 0;
            __syncthreads();
            tmp[threadIdx.x] += add;
            __syncthreads();
        }
        int incl = tmp[threadIdx.x];
        int carry = carry_s;
        if (i < nb) bsums[i] = incl - v + carry;
        __syncthreads();
        if (threadIdx.x == 0) carry_s = carry + tmp[1023];
        __syncthreads();
    }
}

__global__ void scan3_kernel(int* __restrict__ out, const int* __restrict__ bsums, int n) {
    int t = blockIdx.x * SCAN_B + threadIdx.x;
    if (t < n) out[t] += bsums[blockIdx.x];
}

__global__ void gather_kernel(const float4* __restrict__ h4, const int* __restrict__ csr_src,
                              const int* __restrict__ offset, const int* __restrict__ deg_dst,
                              const float* __restrict__ norm_src,
                              float4* __restrict__ out4, int n_dst) {
    int gid = blockIdx.x * blockDim.x + threadIdx.x;
    int row = gid >> 6;
    if (row >= n_dst) return;
    int lane = threadIdx.x & 63;
    int g = lane >> 4;
    int l16 = lane & 15;
    int beg = offset[row];
    int deg = deg_dst[row];
    int end = beg + deg;
    float ax = 0.f, ay = 0.f, az = 0.f, aw = 0.f;
    for (int k = beg + g; k < end; k += 4) {
        int s = csr_src[k];
        float ns = norm_src[s];
        float4 v = h4[s * 16 + l16];
        ax = fmaf(v.x, ns, ax);
        ay = fmaf(v.y, ns, ay);
        az = fmaf(v.z, ns, az);
        aw = fmaf(v.w, ns, aw);
    }
    ax += __shfl_xor(ax, 16); ay += __shfl_xor(ay, 16);
    az += __shfl_xor(az, 16); aw += __shfl_xor(aw, 16);
    ax += __shfl_xor(ax, 32); ay += __shfl_xor(ay, 32);
    az += __shfl_xor(az, 32); aw += __shfl_xor(aw, 32);
    if (g == 0) {
        int dg = deg < 1 ? 1 : deg;
        float nd = 1.0f / (float)dg;
        float4 r;
        r.x = ax * nd; r.y = ay * nd; r.z = az * nd; r.w = aw * nd;
        out4[row * 16 + l16] = r;
    }
}

__global__ void degree_kernel(const int* __restrict__ src, const int* __restrict__ dst,
                              int E, int* __restrict__ deg_src, int* __restrict__ deg_dst) {
    int t = blockIdx.x * blockDim.x + threadIdx.x;
    int base = t * 4;
    if (base + 3 < E) {
        int4 s = *(const int4*)(src + base);
        int4 d = *(const int4*)(dst + base);
        atomicAdd(&deg_src[s.x], 1); atomicAdd(&deg_src[s.y], 1);
        atomicAdd(&deg_src[s.z], 1); atomicAdd(&deg_src[s.w], 1);
        atomicAdd(&deg_dst[d.x], 1); atomicAdd(&deg_dst[d.y], 1);
        atomicAdd(&deg_dst[d.z], 1); atomicAdd(&deg_dst[d.w], 1);
    } else {
        for (int i = base; i < E; ++i) {
            atomicAdd(&deg_src[src[i]], 1);
            atomicAdd(&deg_dst[dst[i]], 1);
        }
    }
}

__global__ void norm_src_kernel(const int* __restrict__ deg_src, int n_src,
                                float* __restrict__ norm_src) {
    int t = blockIdx.x * blockDim.x + threadIdx.x;
    if (t < n_src) {
        int s = deg_src[t]; if (s < 1) s = 1;
        norm_src[t] = 1.0f / (float)s;
    }
}

__global__ void fill_kernel(const int* __restrict__ src, const int* __restrict__ dst, int E,
                            const int* __restrict__ offset, int* __restrict__ cursor,
                            int* __restrict__ csr_src) {
    int t = blockIdx.x * blockDim.x + threadIdx.x;
    int base = t * 4;
    if (base + 3 < E) {
        int4 s = *(const int4*)(src + base);
        int4 d = *(const int4*)(dst + base);
        int p;
        p = offset[d.x] + atomicAdd(&cursor[d.x], 1); csr_src[p] = s.x;
        p = offset[d.y] + atomicAdd(&cursor[d.y], 1); csr_src[p] = s.y;
        p = offset[d.z] + atomicAdd(&cursor[d.z], 1); csr_src[p] = s.z;
        p = offset[d.w] + atomicAdd(&cursor[d.w], 1); csr_src[p] = s.w;
    } else {
        for (int i = base; i < E; ++i) {
            int d = dst[i];
            int p = offset[d] + atomicAdd(&cursor[d], 1);
            csr_src[p] = src[i];
        }
    }
}

__global__ void scatter_kernel(const float* __restrict__ h,
                               const int* __restrict__ src, const int* __restrict__ dst,
                               const float* __restrict__ norm_src,
                               float* __restrict__ out, int E) {
    long long t = (long long)blockIdx.x * blockDim.x + threadIdx.x;
    int e = (int)(t >> 6);
    if (e >= E) return;
    int j = (int)(t & 63);
    int s = src[e];
    float v = h[s * D + j] * norm_src[s];
    unsafeAtomicAdd(&out[dst[e] * D + j], v);
}

__global__ void scale_kernel(float* __restrict__ out, const int* __restrict__ deg_dst, int n) {
    int t = blockIdx.x * blockDim.x + threadIdx.x;
    if (t < n) {
        int dg = deg_dst[t >> 6]; if (dg < 1) dg = 1;
        out[t] *= 1.0f / (float)dg;
    }
}

static inline size_t align16(size_t x) { return (x + 15) & ~(size_t)15; }

extern "C" void kernel_launch(void* const* d_in, const int* in_sizes, int n_in,
                              void* d_out, int out_size, void* d_ws, size_t ws_size,
                              hipStream_t stream) {
    const float* h   = (const float*)d_in[0];
    const int*   src = (const int*)d_in[1];
    const int*   dst = (const int*)d_in[2];
    float* out = (float*)d_out;

    const int E     = in_sizes[1];
    const int n_src = in_sizes[0] / D;
    const int n_dst = out_size / D;
    const int n_cnt = 2 * NBUCK * NCHUNK;            // 131072
    int epc = (E + NCHUNK - 1) / NCHUNK;
    epc = (epc + 3) & ~3;                            // 16B-aligned chunk bases

    // ---- Path A: radix-256/512 sort + bf16-feat precompute + 2-row gather ----
    char* w = (char*)d_ws;
    size_t off = 0;
    size_t o_cnt   = off; off = align16(off + (size_t)n_cnt * 4);
    size_t o_btot  = off; off = align16(off + (size_t)(2 * NBUCK) * 4);
    size_t o_btotS = off; off = align16(off + (size_t)(2 * NBUCK) * 4);
    size_t o_packD = off; off = align16(off + (size_t)E * 4);
    size_t o_csr   = off; off = align16(off + (size_t)E * 4);
    size_t o_od    = off; off = align16(off + (size_t)n_dst * 8);
    size_t o_feat  = off; off = align16(off + (size_t)n_src * 64 * 2);
    size_t o_srtS  = off; off = align16(off + (size_t)E * 2);
    size_t needA = off;

    if (ws_size >= needA && n_src <= NBUCK * 512 && n_dst <= NBUCK * 512) {
        int* cnt    = (int*)(w + o_cnt);
        int* btot   = (int*)(w + o_btot);
        int* btotS  = (int*)(w + o_btotS);
        int* packD  = (int*)(w + o_packD);
        int* csr    = (int*)(w + o_csr);
        int2* od    = (int2*)(w + o_od);
        unsigned short* featb = (unsigned short*)(w + o_feat);
        unsigned short* srtS  = (unsigned short*)(w + o_srtS);

        p1_count<<<NCHUNK, 1024, 0, stream>>>(src, dst, E, epc, cnt);
        scanA_kernel<<<2 * NBUCK, NCHUNK, 0, stream>>>(cnt, btot);
        p2_scatter<<<NCHUNK, 1024, 0, stream>>>(src, dst, E, epc, cnt, btot, btotS,
                                                packD, srtS);
        p3_merged<<<2 * NBUCK, 512, 0, stream>>>(packD, srtS, btotS, h,
                                                 E, n_dst, n_src, csr, od, featb);
        long long gthreads = (long long)n_dst * 32;
        gather_feat<<<(int)((gthreads + 255) / 256), 256, 0, stream>>>(
            featb, csr, od, out, n_dst);
        return;
    }

    // ---- Path B: CSR via device atomics ----
    const int nbB = (n_dst + SCAN_B - 1) / SCAN_B;
    const int nbB_pad = ((nbB + 1023) / 1024) * 1024;
    const int eb4 = (E + 4 * 256 - 1) / (4 * 256);
    const int nblk = ((n_src > n_dst ? n_src : n_dst) + 255) / 256;
    size_t needB = ((size_t)n_src * 2 + (size_t)n_dst * 3 + nbB_pad) * 4 + (size_t)E * 4;

    if (ws_size >= needB) {
        int* deg_src = (int*)d_ws;
        int* deg_dst = deg_src + n_src;
        int* cursor  = deg_dst + n_dst;
        int* offset  = cursor + n_dst;
        int* bsums   = offset + n_dst;
        float* norm_src = (float*)(bsums + nbB_pad);
        int* csr_src = (int*)(norm_src + n_src);

        (void)hipMemsetAsync(d_ws, 0, sizeof(int) * (size_t)(n_src + 2 * (size_t)n_dst), stream);
        degree_kernel<<<eb4, 256, 0, stream>>>(src, dst, E, deg_src, deg_dst);
        norm_src_kernel<<<nblk, 256, 0, stream>>>(deg_src, n_src, norm_src);
        scan1_kernel<<<nbB, SCAN_B, 0, stream>>>(deg_dst, n_dst, offset, bsums);
        scan2_kernel<<<1, 1024, 0, stream>>>(bsums, nbB);
        scan3_kernel<<<nbB, SCAN_B, 0, stream>>>(offset, bsums, n_dst);
        fill_kernel<<<eb4, 256, 0, stream>>>(src, dst, E, offset, cursor, csr_src);
        long long gthreads = (long long)n_dst * D;
        gather_kernel<<<(int)((gthreads + 255) / 256), 256, 0, stream>>>(
            (const float4*)h, csr_src, offset, deg_dst, norm_src, (float4*)out, n_dst);
        return;
    }

    // ---- Path C: minimal atomic scatter ----
    {
        int* deg_src = (int*)d_ws;
        int* deg_dst = deg_src + n_src;
        float* norm_src = (float*)(deg_dst + n_dst);
        (void)hipMemsetAsync(d_ws, 0, sizeof(int) * (size_t)(n_src + n_dst), stream);
        (void)hipMemsetAsync(d_out, 0, sizeof(float) * (size_t)out_size, stream);
        degree_kernel<<<eb4, 256, 0, stream>>>(src, dst, E, deg_src, deg_dst);
        norm_src_kernel<<<nblk, 256, 0, stream>>>(deg_src, n_src, norm_src);
        long long total = (long long)E * D;
        scatter_kernel<<<(int)((total + 255) / 256), 256, 0, stream>>>(h, src, dst, norm_src, out, E);
        scale_kernel<<<(out_size + 255) / 256, 256, 0, stream>>>(out, deg_dst, out_size);
    }
}

// Round 17
// 84.112 us; speedup vs baseline: 1.7167x; 1.2546x over previous
//
#include <hip/hip_runtime.h>

#define D 64
#define SCAN_B 256
#define NBUCK 256    // coarse buckets: key >> 9
#define BSH 9
#define BMSK 511     // second-level bins per bucket
#define NCHUNK 256   // edge chunks for count/scatter passes

typedef __attribute__((ext_vector_type(8))) unsigned short ushort8_t;

__device__ __forceinline__ unsigned short f2bf(float f) {
    unsigned u = __float_as_uint(f);
    unsigned r = (u + 0x7FFFu + ((u >> 16) & 1u)) >> 16;   // RNE
    return (unsigned short)r;
}
__device__ __forceinline__ float uf(unsigned u) { return __uint_as_float(u); }

// ================= Path A: atomic-free two-level counting sort =================

// P1: per (bucket, chunk) counts for dst and src, bucket-major layout.
// 1024 threads, int4 edge reads (epc multiple of 4 -> aligned).
__global__ __launch_bounds__(1024) void p1_count(
        const int* __restrict__ src, const int* __restrict__ dst, int E,
        int epc, int* __restrict__ cnt) {
    __shared__ int cd[NBUCK], cs[NBUCK];
    int c = blockIdx.x;
    int t = threadIdx.x;
    if (t < NBUCK) { cd[t] = 0; cs[t] = 0; }
    __syncthreads();
    int beg = c * epc;
    int end = min(E, beg + epc);
    if (beg < end) {
        int n = end - beg;
        int nq = n >> 2;
        for (int q = t; q < nq; q += 1024) {
            int4 s4 = *(const int4*)(src + beg + q * 4);
            int4 d4 = *(const int4*)(dst + beg + q * 4);
            atomicAdd(&cd[((unsigned)d4.x) >> BSH], 1);
            atomicAdd(&cd[((unsigned)d4.y) >> BSH], 1);
            atomicAdd(&cd[((unsigned)d4.z) >> BSH], 1);
            atomicAdd(&cd[((unsigned)d4.w) >> BSH], 1);
            atomicAdd(&cs[((unsigned)s4.x) >> BSH], 1);
            atomicAdd(&cs[((unsigned)s4.y) >> BSH], 1);
            atomicAdd(&cs[((unsigned)s4.z) >> BSH], 1);
            atomicAdd(&cs[((unsigned)s4.w) >> BSH], 1);
        }
        for (int i = beg + nq * 4 + t; i < end; i += 1024) {
            atomicAdd(&cd[((unsigned)dst[i]) >> BSH], 1);
            atomicAdd(&cs[((unsigned)src[i]) >> BSH], 1);
        }
    }
    __syncthreads();
    if (t < NBUCK) {
        cnt[(size_t)t * NCHUNK + c] = cd[t];
        cnt[(size_t)(NBUCK + t) * NCHUNK + c] = cs[t];
    }
}

// scanA: one block per bucket-row (2*NBUCK rows): exclusive scan of NCHUNK counts
// in place; RAW row total -> btot[row].
__global__ void scanA_kernel(int* __restrict__ cnt, int* __restrict__ btot) {
    __shared__ int lds[NCHUNK];
    int g = blockIdx.x;
    int* e = cnt + (size_t)g * NCHUNK;
    int t = threadIdx.x;
    int v = e[t];
    lds[t] = v;
    __syncthreads();
    for (int off = 1; off < NCHUNK; off <<= 1) {
        int add = (t >= off) ? lds[t - off] : 0;
        __syncthreads();
        lds[t] += add;
        __syncthreads();
    }
    int incl = lds[t];
    e[t] = incl - v;                 // exclusive within row
    if (t == NCHUNK - 1) btot[g] = incl;   // raw total (scanned in p2)
}

// P2: scans the 512 raw row totals in LDS (block 0 publishes to btotS), then
// scatters edges into bucket-partitioned arrays via LDS cursors. 1024 threads.
__global__ __launch_bounds__(1024) void p2_scatter(
        const int* __restrict__ src, const int* __restrict__ dst, int E,
        int epc, const int* __restrict__ cnt, const int* __restrict__ btot,
        int* __restrict__ btotS,
        int* __restrict__ packD, unsigned short* __restrict__ srtS) {
    __shared__ int scn[2 * NBUCK];   // 512
    __shared__ int curD[NBUCK], curS[NBUCK];
    int c = blockIdx.x;
    int t = threadIdx.x;
    int raw = 0;
    if (t < 2 * NBUCK) { raw = btot[t]; scn[t] = raw; }
    __syncthreads();
    for (int off = 1; off < 2 * NBUCK; off <<= 1) {
        int v = 0;
        if (t < 2 * NBUCK && t >= off) v = scn[t - off];
        __syncthreads();
        if (t < 2 * NBUCK) scn[t] += v;
        __syncthreads();
    }
    int excl = 0;
    if (t < 2 * NBUCK) excl = scn[t] - raw;
    __syncthreads();
    if (t < 2 * NBUCK) scn[t] = excl;
    __syncthreads();
    if (c == 0 && t < 2 * NBUCK) btotS[t] = excl;
    if (t < NBUCK) {
        curD[t] = scn[t] + cnt[(size_t)t * NCHUNK + c];
        curS[t] = scn[NBUCK + t] + cnt[(size_t)(NBUCK + t) * NCHUNK + c] - E;
    }
    __syncthreads();
    int beg = c * epc;
    int end = min(E, beg + epc);
    for (int i = beg + t; i < end; i += 1024) {
        int d = dst[i], s = src[i];
        int pd = atomicAdd(&curD[((unsigned)d) >> BSH], 1);
        packD[pd] = (s << BSH) | (d & BMSK);
        int ps = atomicAdd(&curS[((unsigned)s) >> BSH], 1);
        srtS[ps] = (unsigned short)(s & BMSK);
    }
}

// P3 merged: blocks [0,NBUCK) place dst CSR (512-bin hist + pair scan);
// blocks [NBUCK,2*NBUCK) compute src norms AND write feat(bf16)=h*norm.
__global__ __launch_bounds__(512) void p3_merged(
        const int* __restrict__ packD, const unsigned short* __restrict__ srtS,
        const int* __restrict__ btot, const float4* __restrict__ h4,
        int E, int n_dst, int n_src,
        int* __restrict__ csr, int2* __restrict__ od_arr,
        unsigned short* __restrict__ featb) {
    __shared__ int hist[512];
    __shared__ int scan_s[256];
    __shared__ float nrm[512];
    int blk = blockIdx.x;
    int t = threadIdx.x;
    if (blk < NBUCK) {
        int b = blk;
        int beg = btot[b];
        int end = btot[b + 1];          // btot[NBUCK] == E
        hist[t] = 0;
        __syncthreads();
        for (int i = beg + t; i < end; i += 512)
            atomicAdd(&hist[packD[i] & BMSK], 1);
        __syncthreads();
        int a0 = 0, a1 = 0, p = 0;
        if (t < 256) {
            a0 = hist[2 * t]; a1 = hist[2 * t + 1];
            p = a0 + a1;
            scan_s[t] = p;
        }
        __syncthreads();
        for (int off = 1; off < 256; off <<= 1) {
            int v = 0;
            if (t < 256 && t >= off) v = scan_s[t - off];
            __syncthreads();
            if (t < 256) scan_s[t] += v;
            __syncthreads();
        }
        if (t < 256) {
            int e0 = scan_s[t] - p;
            int dbin0 = b * 512 + 2 * t;
            int dbin1 = dbin0 + 1;
            if (dbin0 < n_dst) od_arr[dbin0] = make_int2(beg + e0, a0);
            if (dbin1 < n_dst) od_arr[dbin1] = make_int2(beg + e0 + a0, a1);
            hist[2 * t] = e0;               // becomes cursor
            hist[2 * t + 1] = e0 + a0;
        }
        __syncthreads();
        for (int i = beg + t; i < end; i += 512) {
            int v = packD[i];
            int pos = beg + atomicAdd(&hist[v & BMSK], 1);
            csr[pos] = v >> BSH;
        }
    } else {
        int row = blk;                  // NBUCK..2*NBUCK-1
        int b = blk - NBUCK;
        int beg = btot[row] - E;
        int end = ((row + 1 < 2 * NBUCK) ? btot[row + 1] : 2 * E) - E;
        hist[t] = 0;
        __syncthreads();
        for (int i = beg + t; i < end; i += 512)
            atomicAdd(&hist[srtS[i]], 1);
        __syncthreads();
        {
            int h0 = hist[t]; if (h0 < 1) h0 = 1;
            nrm[t] = 1.0f / (float)h0;
        }
        __syncthreads();
        for (int i = t; i < 512 * 8; i += 512) {
            int r = i >> 3, l8 = i & 7;
            int gsrc = b * 512 + r;
            if (gsrc < n_src) {
                float nm = nrm[r];
                float4 v0 = h4[(size_t)gsrc * 16 + l8 * 2];
                float4 v1 = h4[(size_t)gsrc * 16 + l8 * 2 + 1];
                ushort8_t o;
                o[0] = f2bf(v0.x * nm); o[1] = f2bf(v0.y * nm);
                o[2] = f2bf(v0.z * nm); o[3] = f2bf(v0.w * nm);
                o[4] = f2bf(v1.x * nm); o[5] = f2bf(v1.y * nm);
                o[6] = f2bf(v1.z * nm); o[7] = f2bf(v1.w * nm);
                *(ushort8_t*)(featb + (size_t)gsrc * 64 + l8 * 8) = o;
            }
        }
    }
}

#define ACC(v) do { \
    a[0] += uf((v).x << 16); a[1] += uf((v).x & 0xFFFF0000u); \
    a[2] += uf((v).y << 16); a[3] += uf((v).y & 0xFFFF0000u); \
    a[4] += uf((v).z << 16); a[5] += uf((v).z & 0xFFFF0000u); \
    a[6] += uf((v).w << 16); a[7] += uf((v).w & 0xFFFF0000u); } while (0)

// gather: TWO rows per wave (32 lanes/row); 4 edge-groups x 8 lanes x 16B,
// unroll 4 -> 16 edges in flight per row (32 per wave). Regular loads/stores.
__global__ void gather_feat(const unsigned short* __restrict__ featb,
                            const int* __restrict__ csr,
                            const int2* __restrict__ od_arr,
                            float4* __restrict__ out4, int n_dst) {
    int gid = blockIdx.x * blockDim.x + threadIdx.x;
    int row = gid >> 5;
    if (row >= n_dst) return;
    int lane = threadIdx.x & 31;
    int g = lane >> 3;       // edge group 0..3
    int l8 = lane & 7;       // 16B slot within 128B row
    int2 od = od_arr[row];
    int beg = od.x, dg = od.y;
    int end = beg + dg;
    float a[8] = {0.f, 0.f, 0.f, 0.f, 0.f, 0.f, 0.f, 0.f};
    int k = beg + g;
    for (; k + 12 < end; k += 16) {
        int s0 = csr[k];
        int s1 = csr[k + 4];
        int s2 = csr[k + 8];
        int s3 = csr[k + 12];
        uint4 v0 = *(const uint4*)(featb + (size_t)s0 * 64 + l8 * 8);
        uint4 v1 = *(const uint4*)(featb + (size_t)s1 * 64 + l8 * 8);
        uint4 v2 = *(const uint4*)(featb + (size_t)s2 * 64 + l8 * 8);
        uint4 v3 = *(const uint4*)(featb + (size_t)s3 * 64 + l8 * 8);
        ACC(v0); ACC(v1); ACC(v2); ACC(v3);
    }
    for (; k < end; k += 4) {
        int s0 = csr[k];
        uint4 v0 = *(const uint4*)(featb + (size_t)s0 * 64 + l8 * 8);
        ACC(v0);
    }
    // reduce across the 4 groups (lane bits 3,4) — stays within 32-lane half
    #pragma unroll
    for (int j = 0; j < 8; ++j) a[j] += __shfl_xor(a[j], 8);
    #pragma unroll
    for (int j = 0; j < 8; ++j) a[j] += __shfl_xor(a[j], 16);
    if (g == 0) {
        float nd = 1.0f / (float)(dg < 1 ? 1 : dg);
        float4 r0, r1;
        r0.x = a[0] * nd; r0.y = a[1] * nd; r0.z = a[2] * nd; r0.w = a[3] * nd;
        r1.x = a[4] * nd; r1.y = a[5] * nd; r1.z = a[6] * nd; r1.w = a[7] * nd;
        out4[(size_t)row * 16 + l8 * 2]     = r0;
        out4[(size_t)row * 16 + l8 * 2 + 1] = r1;
    }
}

// ====================== legacy kernels (paths B/C) ======================
__global__ void scan1_kernel(const int* __restrict__ deg, int n,
                             int* __restrict__ out, int* __restrict__ bsums) {
    __shared__ int tmp[SCAN_B];
    int t = blockIdx.x * SCAN_B + threadIdx.x;
    int v = (t < n) ? deg[t] : 0;
    tmp[threadIdx.x] = v;
    __syncthreads();
    for (int off = 1; off < SCAN_B; off <<= 1) {
        int add = (threadIdx.x >= off) ? tmp[threadIdx.x - off] : 0;
        __syncthreads();
        tmp[threadIdx.x] += add;
        __syncthreads();
    }
    if (t < n) out[t] = tmp[threadIdx.x] - v;
    if (threadIdx.x == SCAN_B - 1) bsums[blockIdx.x] = tmp[threadIdx.x];
}

__global__ void scan2_kernel(int* __restrict__ bsums, int nb) {
    __shared__ int tmp[1024];
    __shared__ int carry_s;
    if (threadIdx.x == 0) carry_s = 0;
    __syncthreads();
    for (int base = 0; base < nb; base += 1024) {
        int i = base + threadIdx.x;
        int v = (i < nb) ? bsums[i] : 0;
        tmp[threadIdx.x] = v;
        __syncthreads();
        for (int off = 1; off < 1024; off <<= 1) {
            int add = (threadIdx.x >= off) ? tmp[threadIdx.x - off] : 0;
            __syncthreads();
            tmp[threadIdx.x] += add;
            __syncthreads();
        }
        int incl = tmp[threadIdx.x];
        int carry = carry_s;
        if (i < nb) bsums[i] = incl - v + carry;
        __syncthreads();
        if (threadIdx.x == 0) carry_s = carry + tmp[1023];
        __syncthreads();
    }
}

__global__ void scan3_kernel(int* __restrict__ out, const int* __restrict__ bsums, int n) {
    int t = blockIdx.x * SCAN_B + threadIdx.x;
    if (t < n) out[t] += bsums[blockIdx.x];
}

__global__ void gather_kernel(const float4* __restrict__ h4, const int* __restrict__ csr_src,
                              const int* __restrict__ offset, const int* __restrict__ deg_dst,
                              const float* __restrict__ norm_src,
                              float4* __restrict__ out4, int n_dst) {
    int gid = blockIdx.x * blockDim.x + threadIdx.x;
    int row = gid >> 6;
    if (row >= n_dst) return;
    int lane = threadIdx.x & 63;
    int g = lane >> 4;
    int l16 = lane & 15;
    int beg = offset[row];
    int deg = deg_dst[row];
    int end = beg + deg;
    float ax = 0.f, ay = 0.f, az = 0.f, aw = 0.f;
    for (int k = beg + g; k < end; k += 4) {
        int s = csr_src[k];
        float ns = norm_src[s];
        float4 v = h4[s * 16 + l16];
        ax = fmaf(v.x, ns, ax);
        ay = fmaf(v.y, ns, ay);
        az = fmaf(v.z, ns, az);
        aw = fmaf(v.w, ns, aw);
    }
    ax += __shfl_xor(ax, 16); ay += __shfl_xor(ay, 16);
    az += __shfl_xor(az, 16); aw += __shfl_xor(aw, 16);
    ax += __shfl_xor(ax, 32); ay += __shfl_xor(ay, 32);
    az += __shfl_xor(az, 32); aw += __shfl_xor(aw, 32);
    if (g == 0) {
        int dg = deg < 1 ? 1 : deg;
        float nd = 1.0f / (float)dg;
        float4 r;
        r.x = ax * nd; r.y = ay * nd; r.z = az * nd; r.w = aw * nd;
        out4[row * 16 + l16] = r;
    }
}

__global__ void degree_kernel(const int* __restrict__ src, const int* __restrict__ dst,
                              int E, int* __restrict__ deg_src, int* __restrict__ deg_dst) {
    int t = blockIdx.x * blockDim.x + threadIdx.x;
    int base = t * 4;
    if (base + 3 < E) {
        int4 s = *(const int4*)(src + base);
        int4 d = *(const int4*)(dst + base);
        atomicAdd(&deg_src[s.x], 1); atomicAdd(&deg_src[s.y], 1);
        atomicAdd(&deg_src[s.z], 1); atomicAdd(&deg_src[s.w], 1);
        atomicAdd(&deg_dst[d.x], 1); atomicAdd(&deg_dst[d.y], 1);
        atomicAdd(&deg_dst[d.z], 1); atomicAdd(&deg_dst[d.w], 1);
    } else {
        for (int i = base; i < E; ++i) {
            atomicAdd(&deg_src[src[i]], 1);
            atomicAdd(&deg_dst[dst[i]], 1);
        }
    }
}

__global__ void norm_src_kernel(const int* __restrict__ deg_src, int n_src,
                                float* __restrict__ norm_src) {
    int t = blockIdx.x * blockDim.x + threadIdx.x;
    if (t < n_src) {
        int s = deg_src[t]; if (s < 1) s = 1;
        norm_src[t] = 1.0f / (float)s;
    }
}

__global__ void fill_kernel(const int* __restrict__ src, const int* __restrict__ dst, int E,
                            const int* __restrict__ offset, int* __restrict__ cursor,
                            int* __restrict__ csr_src) {
    int t = blockIdx.x * blockDim.x + threadIdx.x;
    int base = t * 4;
    if (base + 3 < E) {
        int4 s = *(const int4*)(src + base);
        int4 d = *(const int4*)(dst + base);
        int p;
        p = offset[d.x] + atomicAdd(&cursor[d.x], 1); csr_src[p] = s.x;
        p = offset[d.y] + atomicAdd(&cursor[d.y], 1); csr_src[p] = s.y;
        p = offset[d.z] + atomicAdd(&cursor[d.z], 1); csr_src[p] = s.z;
        p = offset[d.w] + atomicAdd(&cursor[d.w], 1); csr_src[p] = s.w;
    } else {
        for (int i = base; i < E; ++i) {
            int d = dst[i];
            int p = offset[d] + atomicAdd(&cursor[d], 1);
            csr_src[p] = src[i];
        }
    }
}

__global__ void scatter_kernel(const float* __restrict__ h,
                               const int* __restrict__ src, const int* __restrict__ dst,
                               const float* __restrict__ norm_src,
                               float* __restrict__ out, int E) {
    long long t = (long long)blockIdx.x * blockDim.x + threadIdx.x;
    int e = (int)(t >> 6);
    if (e >= E) return;
    int j = (int)(t & 63);
    int s = src[e];
    float v = h[s * D + j] * norm_src[s];
    unsafeAtomicAdd(&out[dst[e] * D + j], v);
}

__global__ void scale_kernel(float* __restrict__ out, const int* __restrict__ deg_dst, int n) {
    int t = blockIdx.x * blockDim.x + threadIdx.x;
    if (t < n) {
        int dg = deg_dst[t >> 6]; if (dg < 1) dg = 1;
        out[t] *= 1.0f / (float)dg;
    }
}

static inline size_t align16(size_t x) { return (x + 15) & ~(size_t)15; }

extern "C" void kernel_launch(void* const* d_in, const int* in_sizes, int n_in,
                              void* d_out, int out_size, void* d_ws, size_t ws_size,
                              hipStream_t stream) {
    const float* h   = (const float*)d_in[0];
    const int*   src = (const int*)d_in[1];
    const int*   dst = (const int*)d_in[2];
    float* out = (float*)d_out;

    const int E     = in_sizes[1];
    const int n_src = in_sizes[0] / D;
    const int n_dst = out_size / D;
    const int n_cnt = 2 * NBUCK * NCHUNK;            // 131072
    int epc = (E + NCHUNK - 1) / NCHUNK;
    epc = (epc + 3) & ~3;                            // 16B-aligned chunk bases

    // ---- Path A: radix-256/512 sort + bf16-feat precompute + 2-row gather ----
    char* w = (char*)d_ws;
    size_t off = 0;
    size_t o_cnt   = off; off = align16(off + (size_t)n_cnt * 4);
    size_t o_btot  = off; off = align16(off + (size_t)(2 * NBUCK) * 4);
    size_t o_btotS = off; off = align16(off + (size_t)(2 * NBUCK) * 4);
    size_t o_packD = off; off = align16(off + (size_t)E * 4);
    size_t o_csr   = off; off = align16(off + (size_t)E * 4);
    size_t o_od    = off; off = align16(off + (size_t)n_dst * 8);
    size_t o_feat  = off; off = align16(off + (size_t)n_src * 64 * 2);
    size_t o_srtS  = off; off = align16(off + (size_t)E * 2);
    size_t needA = off;

    if (ws_size >= needA && n_src <= NBUCK * 512 && n_dst <= NBUCK * 512) {
        int* cnt    = (int*)(w + o_cnt);
        int* btot   = (int*)(w + o_btot);
        int* btotS  = (int*)(w + o_btotS);
        int* packD  = (int*)(w + o_packD);
        int* csr    = (int*)(w + o_csr);
        int2* od    = (int2*)(w + o_od);
        unsigned short* featb = (unsigned short*)(w + o_feat);
        unsigned short* srtS  = (unsigned short*)(w + o_srtS);

        p1_count<<<NCHUNK, 1024, 0, stream>>>(src, dst, E, epc, cnt);
        scanA_kernel<<<2 * NBUCK, NCHUNK, 0, stream>>>(cnt, btot);
        p2_scatter<<<NCHUNK, 1024, 0, stream>>>(src, dst, E, epc, cnt, btot, btotS,
                                                packD, srtS);
        p3_merged<<<2 * NBUCK, 512, 0, stream>>>(packD, srtS, btotS, (const float4*)h,
                                                 E, n_dst, n_src, csr, od, featb);
        long long gthreads = (long long)n_dst * 32;
        gather_feat<<<(int)((gthreads + 255) / 256), 256, 0, stream>>>(
            featb, csr, od, (float4*)out, n_dst);
        return;
    }

    // ---- Path B: CSR via device atomics ----
    const int nbB = (n_dst + SCAN_B - 1) / SCAN_B;
    const int nbB_pad = ((nbB + 1023) / 1024) * 1024;
    const int eb4 = (E + 4 * 256 - 1) / (4 * 256);
    const int nblk = ((n_src > n_dst ? n_src : n_dst) + 255) / 256;
    size_t needB = ((size_t)n_src * 2 + (size_t)n_dst * 3 + nbB_pad) * 4 + (size_t)E * 4;

    if (ws_size >= needB) {
        int* deg_src = (int*)d_ws;
        int* deg_dst = deg_src + n_src;
        int* cursor  = deg_dst + n_dst;
        int* offset  = cursor + n_dst;
        int* bsums   = offset + n_dst;
        float* norm_src = (float*)(bsums + nbB_pad);
        int* csr_src = (int*)(norm_src + n_src);

        (void)hipMemsetAsync(d_ws, 0, sizeof(int) * (size_t)(n_src + 2 * (size_t)n_dst), stream);
        degree_kernel<<<eb4, 256, 0, stream>>>(src, dst, E, deg_src, deg_dst);
        norm_src_kernel<<<nblk, 256, 0, stream>>>(deg_src, n_src, norm_src);
        scan1_kernel<<<nbB, SCAN_B, 0, stream>>>(deg_dst, n_dst, offset, bsums);
        scan2_kernel<<<1, 1024, 0, stream>>>(bsums, nbB);
        scan3_kernel<<<nbB, SCAN_B, 0, stream>>>(offset, bsums, n_dst);
        fill_kernel<<<eb4, 256, 0, stream>>>(src, dst, E, offset, cursor, csr_src);
        long long gthreads = (long long)n_dst * D;
        gather_kernel<<<(int)((gthreads + 255) / 256), 256, 0, stream>>>(
            (const float4*)h, csr_src, offset, deg_dst, norm_src, (float4*)out, n_dst);
        return;
    }

    // ---- Path C: minimal atomic scatter ----
    {
        int* deg_src = (int*)d_ws;
        int* deg_dst = deg_src + n_src;
        float* norm_src = (float*)(deg_dst + n_dst);
        (void)hipMemsetAsync(d_ws, 0, sizeof(int) * (size_t)(n_src + n_dst), stream);
        (void)hipMemsetAsync(d_out, 0, sizeof(float) * (size_t)out_size, stream);
        degree_kernel<<<eb4, 256, 0, stream>>>(src, dst, E, deg_src, deg_dst);
        norm_src_kernel<<<nblk, 256, 0, stream>>>(deg_src, n_src, norm_src);
        long long total = (long long)E * D;
        scatter_kernel<<<(int)((total + 255) / 256), 256, 0, stream>>>(h, src, dst, norm_src, out, E);
        scale_kernel<<<(out_size + 255) / 256, 256, 0, stream>>>(out, deg_dst, out_size);
    }
}